// Round 10
// baseline (986.212 us; speedup 1.0000x reference)
//
#include <hip/hip_runtime.h>
#include <math.h>

typedef _Float16 f16;
typedef _Float16 f16x2 __attribute__((ext_vector_type(2)));
typedef _Float16 f16x4 __attribute__((ext_vector_type(4)));
typedef _Float16 f16x8 __attribute__((ext_vector_type(8)));
typedef float f32x4 __attribute__((ext_vector_type(4)));

#define G_ 64
#define NP_ 512
#define N_ 32768
#define E_ 524288
#define C_ 128
#define H_ 4
#define HD_ 32
#define L_ 4

static __device__ __forceinline__ float gelu_exact(float x) {
    return 0.5f * x * (1.0f + erff(x * 0.70710678118654752f));
}

// async global->LDS, 16 B per lane; LDS dst = wave-uniform base + lane*16
static __device__ __forceinline__ void gload_lds(const f16* g, f16* l) {
    __builtin_amdgcn_global_load_lds(
        (const __attribute__((address_space(1))) void*)g,
        (__attribute__((address_space(3))) void*)l, 16, 0, 0);
}

// ---------------------------------------------------------------------------
// Weight prep: transpose gine/mlp weights to Bt=[M][K] layout, cast all to f16
// ---------------------------------------------------------------------------
__global__ __launch_bounds__(256) void k_prep(
    const float* __restrict__ g1, const float* __restrict__ g2,
    const float* __restrict__ m1, const float* __restrict__ m2,
    const float* __restrict__ ai, const float* __restrict__ ao,
    f16* __restrict__ g1t, f16* __restrict__ g2t,
    f16* __restrict__ m1t, f16* __restrict__ m2t,
    f16* __restrict__ ait, f16* __restrict__ aot)
{
    int i = blockIdx.x * 256 + threadIdx.x;
    if (i < 131072) {                       // gine_w1 [l][128][256] -> [l][256][128]
        int l = i >> 15, r = i & 32767;
        int k = r >> 8, m = r & 255;
        g1t[l * 32768 + m * 128 + k] = (f16)g1[i];
    } else if (i < 262144) {                // gine_w2 [l][256][128] -> [l][128][256]
        int j = i - 131072;
        int l = j >> 15, r = j & 32767;
        int k = r >> 7, m = r & 127;
        g2t[l * 32768 + m * 256 + k] = (f16)g2[j];
    } else if (i < 393216) {                // mlp_w1 like gine_w1
        int j = i - 262144;
        int l = j >> 15, r = j & 32767;
        int k = r >> 8, m = r & 255;
        m1t[l * 32768 + m * 128 + k] = (f16)m1[j];
    } else if (i < 524288) {                // mlp_w2 like gine_w2
        int j = i - 393216;
        int l = j >> 15, r = j & 32767;
        int k = r >> 7, m = r & 127;
        m2t[l * 32768 + m * 256 + k] = (f16)m2[j];
    } else if (i < 720896) {                // attn_in_w [l][384][128]: already Bt, cast
        int j = i - 524288;
        ait[j] = (f16)ai[j];
    } else if (i < 786432) {                // attn_out_w [l][128][128]: already Bt, cast
        int j = i - 720896;
        aot[j] = (f16)ao[j];
    }
}

// ---------------------------------------------------------------------------
// h0 = x @ np_w + np_b   (wave per node, 2 channels per lane)
// ---------------------------------------------------------------------------
__global__ __launch_bounds__(256) void k_h0(const float* __restrict__ x,
    const float* __restrict__ w, const float* __restrict__ b,
    f16* __restrict__ h16)
{
    const int tid = threadIdx.x;
    const int lane = tid & 63, wid = tid >> 6;
    const int node = blockIdx.x * 4 + wid;
    const int c2 = lane * 2;
    float a0 = b[c2], a1 = b[c2 + 1];
    const float* xr = x + (size_t)node * 32;
#pragma unroll
    for (int k = 0; k < 32; k++) {
        float xv = xr[k];
        a0 += xv * w[k * 128 + c2];
        a1 += xv * w[k * 128 + c2 + 1];
    }
    f16x2 z; z[0] = (f16)a0; z[1] = (f16)a1;
    *(f16x2*)(h16 + (size_t)node * 128 + c2) = z;
}

// ---------------------------------------------------------------------------
// CSR build (counting sort of edges by dst) — rebuilt every call
// ---------------------------------------------------------------------------
__global__ void k_zero2(int* a, int* b) {
    int i = blockIdx.x * 256 + threadIdx.x;
    a[i] = 0; b[i] = 0;
}
__global__ void k_count(const int* __restrict__ ei, int* __restrict__ counts) {
    int e = blockIdx.x * 256 + threadIdx.x;
    atomicAdd(&counts[ei[E_ + e]], 1);
}
__global__ __launch_bounds__(1024) void k_scan(const int* __restrict__ counts,
                                               int* __restrict__ rowp)
{
    __shared__ int part[1024];
    const int t = threadIdx.x;
    int s = 0;
#pragma unroll
    for (int i = 0; i < 32; i++) s += counts[t * 32 + i];
    part[t] = s;
    __syncthreads();
    for (int off = 1; off < 1024; off <<= 1) {
        int u = (t >= off) ? part[t - off] : 0;
        __syncthreads();
        part[t] += u;
        __syncthreads();
    }
    int run = part[t] - s;  // exclusive prefix of this chunk
    for (int i = 0; i < 32; i++) {
        int c = counts[t * 32 + i];
        rowp[t * 32 + i] = run;
        run += c;
    }
    if (t == 1023) rowp[N_] = part[1023];
}
__global__ void k_fill(const int* __restrict__ ei, const int* __restrict__ rowp,
                       int* __restrict__ cursor, int* __restrict__ srcp,
                       int* __restrict__ eidp)
{
    int e = blockIdx.x * 256 + threadIdx.x;
    int d = ei[E_ + e];
    int p = atomicAdd(&cursor[d], 1);
    int pos = rowp[d] + p;
    srcp[pos] = ei[e];
    eidp[pos] = e;
}

// ---------------------------------------------------------------------------
// Edge embedding, materialized ONCE in CSR-sorted order. XCD-swizzled.
// ---------------------------------------------------------------------------
__global__ __launch_bounds__(256) void k_edge(const float* __restrict__ edge_attr,
    const float* __restrict__ epw, const float* __restrict__ epb,
    const int* __restrict__ eidp, f16* __restrict__ e16p)
{
    __shared__ __align__(16) float rows[4][64][16];  // 16 KB, per-wave regions
    const int tid = threadIdx.x;
    const int lane = tid & 63, wid = tid >> 6;
    const int c2 = lane * 2;
    float w0[16], w1[16];
#pragma unroll
    for (int k = 0; k < 16; k++) {
        w0[k] = epw[k * 128 + c2];
        w1[k] = epw[k * 128 + c2 + 1];
    }
    const float b0 = epb[c2], b1 = epb[c2 + 1];
    const int gidx = blockIdx.x & 63, chunk = blockIdx.x >> 6;
    const int base = (gidx * 32 + chunk) * 256 + wid * 64;
    const int eidv = eidp[base + lane];          // one coalesced load: 64 ids
    const int er = lane >> 2, ec = lane & 3;
#pragma unroll
    for (int u = 0; u < 4; u++) {
        int e = __shfl(eidv, u * 16 + er);
        float4 v = *(const float4*)(edge_attr + (size_t)e * 16 + ec * 4);
        *(float4*)(&rows[wid][u * 16 + er][ec * 4]) = v;
    }
    for (int i = 0; i < 64; i++) {
        const float* r = &rows[wid][i][0];       // broadcast reads (free)
        float4 q0 = *(const float4*)(r);
        float4 q1 = *(const float4*)(r + 4);
        float4 q2 = *(const float4*)(r + 8);
        float4 q3 = *(const float4*)(r + 12);
        float e0 = b0, e1 = b1;
        e0 += q0.x*w0[0] + q0.y*w0[1] + q0.z*w0[2] + q0.w*w0[3]
            + q1.x*w0[4] + q1.y*w0[5] + q1.z*w0[6] + q1.w*w0[7]
            + q2.x*w0[8] + q2.y*w0[9] + q2.z*w0[10] + q2.w*w0[11]
            + q3.x*w0[12] + q3.y*w0[13] + q3.z*w0[14] + q3.w*w0[15];
        e1 += q0.x*w1[0] + q0.y*w1[1] + q0.z*w1[2] + q0.w*w1[3]
            + q1.x*w1[4] + q1.y*w1[5] + q1.z*w1[6] + q1.w*w1[7]
            + q2.x*w1[8] + q2.y*w1[9] + q2.z*w1[10] + q2.w*w1[11]
            + q3.x*w1[12] + q3.y*w1[13] + q3.z*w1[14] + q3.w*w1[15];
        f16x2 z; z[0] = (f16)e0; z[1] = (f16)e1;
        *(f16x2*)(e16p + (size_t)(base + i) * 128 + c2) = z;
    }
}

// ---------------------------------------------------------------------------
// GINE aggregation: zin = (1+eps)*h + sum relu(h[src] + e16p[pos])
// Distance-2 software pipeline; XCD-swizzled per graph.
// ---------------------------------------------------------------------------
__global__ __launch_bounds__(256) void k_aggr(const f16* __restrict__ h16,
    const f16* __restrict__ e16p, const int* __restrict__ srcp,
    const int* __restrict__ rowp, const float* __restrict__ eps, int layer,
    f16* __restrict__ zin)
{
    const int tid = threadIdx.x;
    const int lane = tid & 63, wid = tid >> 6;
    const int node = (blockIdx.x & 63) * 512 + (blockIdx.x >> 6) * 4 + wid;
    const int c2 = lane * 2;
    const int r0 = rowp[node], r1 = rowp[node + 1];
    const int deg = r1 - r0;
    const f16x2 hn = *(const f16x2*)(h16 + (size_t)node * 128 + c2);
    float a0 = 0.f, a1 = 0.f;
    if (deg > 0) {
        const int dd = deg < 64 ? deg : 64;
        const int jm = dd - 1;
        const int srcv = srcp[r0 + (lane < jm ? lane : jm)];
        f16x2 h_c, e_c, h_n, e_n;
        {
            int s = __shfl(srcv, 0);
            h_c = *(const f16x2*)(h16 + (size_t)s * 128 + c2);
            e_c = *(const f16x2*)(e16p + (size_t)r0 * 128 + c2);
            int j1 = 1 < jm ? 1 : jm;
            int s1 = __shfl(srcv, j1);
            h_n = *(const f16x2*)(h16 + (size_t)s1 * 128 + c2);
            e_n = *(const f16x2*)(e16p + (size_t)(r0 + j1) * 128 + c2);
        }
        for (int j = 0; j < dd; ++j) {
            int j2 = j + 2 < jm ? j + 2 : jm;
            int s2 = __shfl(srcv, j2);
            f16x2 h_f = *(const f16x2*)(h16 + (size_t)s2 * 128 + c2);
            f16x2 e_f = *(const f16x2*)(e16p + (size_t)(r0 + j2) * 128 + c2);
            a0 += fmaxf((float)e_c[0] + (float)h_c[0], 0.0f);
            a1 += fmaxf((float)e_c[1] + (float)h_c[1], 0.0f);
            h_c = h_n; e_c = e_n; h_n = h_f; e_n = e_f;
        }
        for (int pos = r0 + 64; pos < r1; ++pos) {
            int s = srcp[pos];
            f16x2 ev = *(const f16x2*)(e16p + (size_t)pos * 128 + c2);
            f16x2 hv = *(const f16x2*)(h16 + (size_t)s * 128 + c2);
            a0 += fmaxf((float)ev[0] + (float)hv[0], 0.0f);
            a1 += fmaxf((float)ev[1] + (float)hv[1], 0.0f);
        }
    }
    const float ep = 1.0f + eps[layer];
    f16x2 z;
    z[0] = (f16)(ep * (float)hn[0] + a0);
    z[1] = (f16)(ep * (float)hn[1] + a1);
    *(f16x2*)(zin + (size_t)node * 128 + c2) = z;
}

// ===========================================================================
// GEMM core v3: 128x128 tiles (64 MFMA/wave per 64 KB staged — 2x density of
// the 64-tile core). Staging via global_load_lds w16 + XOR swizzle. 4 waves
// in 2x2 of 64x64. LDS 64 KB -> 2 blocks/CU; grids >= 512 blocks.
// ===========================================================================

// ---- k_gq: merged gine1 + qkv. Grid (256, 5):
// cb 0-1: u16[.,cb*128..] = gelu(zin @ g1t^T + b); cb 2-4: qkv from h16.
__global__ __launch_bounds__(256) void k_gq(
    const f16* __restrict__ zin, const f16* __restrict__ g1t,
    const float* __restrict__ gb1, f16* __restrict__ u16,
    const f16* __restrict__ h16, const f16* __restrict__ ait,
    const float* __restrict__ aib,
    f16* __restrict__ qb, f16* __restrict__ kb, f16* __restrict__ vt)
{
    __shared__ __align__(16) f16 Sm[4096 * 8];       // As 2048 | Bs 2048 chunks
    f16* As = Sm;
    f16* Bs = Sm + 2048 * 8;
    const int tid = threadIdx.x;
    const int lane = tid & 63, wid = tid >> 6;
    const int quad = lane >> 4, l16 = lane & 15;
    const int wm = wid >> 1, wn = wid & 1;
    const int rb = blockIdx.x, cb = blockIdx.y;
    const bool is_qkv = (cb >= 2);
    const int cbl = is_qkv ? (cb - 2) : cb;
    const f16* A  = is_qkv ? h16 : zin;
    const f16* Bt = is_qkv ? ait : g1t;
    const int arow0 = rb * 128, brow0 = cbl * 128;
#pragma unroll
    for (int i = 0; i < 8; i++) {
        int s = i * 256 + wid * 64 + lane;
        int r = s >> 4, cg = (s & 15) ^ (r & 7);
        gload_lds(Bt + (size_t)(brow0 + r) * 128 + cg * 8,
                  Bs + (size_t)(i * 256 + wid * 64) * 8);
    }
#pragma unroll
    for (int i = 0; i < 8; i++) {
        int s = i * 256 + wid * 64 + lane;
        int r = s >> 4, cg = (s & 15) ^ (r & 7);
        gload_lds(A + (size_t)(arow0 + r) * 128 + cg * 8,
                  As + (size_t)(i * 256 + wid * 64) * 8);
    }
    __syncthreads();
    f32x4 acc[4][4];
#pragma unroll
    for (int i = 0; i < 4; i++)
#pragma unroll
        for (int j = 0; j < 4; j++) acc[i][j] = {0.f, 0.f, 0.f, 0.f};
    const int ra0 = wm * 64 + l16, rb0 = wn * 64 + l16;
#pragma unroll
    for (int kc = 0; kc < 4; ++kc) {
        f16x8 af[4], bf[4];
#pragma unroll
        for (int mt = 0; mt < 4; mt++) {
            int r = ra0 + mt * 16;
            af[mt] = *(const f16x8*)(As + (size_t)(r * 16 + ((kc * 4 + quad) ^ (r & 7))) * 8);
        }
#pragma unroll
        for (int nt = 0; nt < 4; nt++) {
            int r = rb0 + nt * 16;
            bf[nt] = *(const f16x8*)(Bs + (size_t)(r * 16 + ((kc * 4 + quad) ^ (r & 7))) * 8);
        }
#pragma unroll
        for (int mt = 0; mt < 4; mt++)
#pragma unroll
            for (int nt = 0; nt < 4; nt++)
                acc[mt][nt] = __builtin_amdgcn_mfma_f32_16x16x32_f16(
                    af[mt], bf[nt], acc[mt][nt], 0, 0, 0);
    }
    if (!is_qkv) {
#pragma unroll
        for (int nt = 0; nt < 4; nt++) {
            const int col = cbl * 128 + wn * 64 + nt * 16 + l16;
            const float bv = gb1[col];
#pragma unroll
            for (int mt = 0; mt < 4; mt++) {
#pragma unroll
                for (int r = 0; r < 4; r++) {
                    const int row = rb * 128 + wm * 64 + mt * 16 + quad * 4 + r;
                    u16[(size_t)row * 256 + col] = (f16)gelu_exact(acc[mt][nt][r] + bv);
                }
            }
        }
    } else if (cbl < 2) {
        f16* outp = cbl ? kb : qb;
#pragma unroll
        for (int nt = 0; nt < 4; nt++) {
            const int col = wn * 64 + nt * 16 + l16;
            const float bv = aib[cbl * 128 + col];
#pragma unroll
            for (int mt = 0; mt < 4; mt++) {
#pragma unroll
                for (int r = 0; r < 4; r++) {
                    const int row = rb * 128 + wm * 64 + mt * 16 + quad * 4 + r;
                    outp[(size_t)row * 128 + col] = (f16)(acc[mt][nt][r] + bv);
                }
            }
        }
    } else {
        const int g = rb >> 2;
#pragma unroll
        for (int nt = 0; nt < 4; nt++) {
            const int coll = wn * 64 + nt * 16 + l16;
            const int h = coll >> 5, d = coll & 31;
            const float bv = aib[256 + coll];
#pragma unroll
            for (int mt = 0; mt < 4; mt++) {
                const int n0 = (rb & 3) * 128 + wm * 64 + mt * 16 + quad * 4;
                f16x4 z;
#pragma unroll
                for (int r = 0; r < 4; r++) z[r] = (f16)(acc[mt][nt][r] + bv);
                *(f16x4*)(vt + ((size_t)((g * 4 + h) * 32 + d)) * 512 + n0) = z;
            }
        }
    }
}

// ---- k_g128: 128-tile KD=128 GEMM for mlp1 with COMB A-fusion.
// A = bn1(r1)+bn2(r2) staged manually, side-written to aout (cb==0).
template <int EPI, bool COMB>
__global__ __launch_bounds__(256) void k_g128(
    const f16* __restrict__ A, const f16* __restrict__ Bt,
    const float* __restrict__ bias,
    const f16* __restrict__ r1, const f16* __restrict__ r2,
    const float* __restrict__ sc1, const float* __restrict__ sc2,
    f16* __restrict__ out, f16* __restrict__ aout, int Mout)
{
    __shared__ __align__(16) f16 Sm[4096 * 8];
    __shared__ float sca[4][128];
    f16* As = Sm;
    f16* Bs = Sm + 2048 * 8;
    const int tid = threadIdx.x;
    const int lane = tid & 63, wid = tid >> 6;
    const int quad = lane >> 4, l16 = lane & 15;
    const int wm = wid >> 1, wn = wid & 1;
    const int rb = blockIdx.x, cb = blockIdx.y;
    const int arow0 = rb * 128, brow0 = cb * 128;
#pragma unroll
    for (int i = 0; i < 8; i++) {
        int s = i * 256 + wid * 64 + lane;
        int r = s >> 4, cg = (s & 15) ^ (r & 7);
        gload_lds(Bt + (size_t)(brow0 + r) * 128 + cg * 8,
                  Bs + (size_t)(i * 256 + wid * 64) * 8);
    }
    if constexpr (!COMB) {
#pragma unroll
        for (int i = 0; i < 8; i++) {
            int s = i * 256 + wid * 64 + lane;
            int r = s >> 4, cg = (s & 15) ^ (r & 7);
            gload_lds(A + (size_t)(arow0 + r) * 128 + cg * 8,
                      As + (size_t)(i * 256 + wid * 64) * 8);
        }
        __syncthreads();
    } else {
        if (tid < 128) { sca[0][tid] = sc1[tid]; sca[1][tid] = sc1[128 + tid]; }
        else { int c = tid - 128; sca[2][c] = sc2[c]; sca[3][c] = sc2[128 + c]; }
        __syncthreads();
#pragma unroll
        for (int j = 0; j < 8; j++) {
            int s = j * 256 + tid;
            int r = s >> 4, cg = (s & 15) ^ (r & 7);
            size_t off = (size_t)(arow0 + r) * 128 + cg * 8;
            f16x8 x1 = *(const f16x8*)(r1 + off);
            f16x8 x2 = *(const f16x8*)(r2 + off);
            f16x8 zc;
#pragma unroll
            for (int i2 = 0; i2 < 8; i2++) {
                int k = cg * 8 + i2;
                float v = (float)x1[i2] * sca[0][k] + sca[1][k]
                        + (float)x2[i2] * sca[2][k] + sca[3][k];
                zc[i2] = (f16)v;
            }
            *(f16x8*)(As + (size_t)s * 8) = zc;
            if (cb == 0) *(f16x8*)(aout + off) = zc;
        }
        __syncthreads();
    }
    f32x4 acc[4][4];
#pragma unroll
    for (int i = 0; i < 4; i++)
#pragma unroll
        for (int j = 0; j < 4; j++) acc[i][j] = {0.f, 0.f, 0.f, 0.f};
    const int ra0 = wm * 64 + l16, rb0 = wn * 64 + l16;
#pragma unroll
    for (int kc = 0; kc < 4; ++kc) {
        f16x8 af[4], bf[4];
#pragma unroll
        for (int mt = 0; mt < 4; mt++) {
            int r = ra0 + mt * 16;
            af[mt] = *(const f16x8*)(As + (size_t)(r * 16 + ((kc * 4 + quad) ^ (r & 7))) * 8);
        }
#pragma unroll
        for (int nt = 0; nt < 4; nt++) {
            int r = rb0 + nt * 16;
            bf[nt] = *(const f16x8*)(Bs + (size_t)(r * 16 + ((kc * 4 + quad) ^ (r & 7))) * 8);
        }
#pragma unroll
        for (int mt = 0; mt < 4; mt++)
#pragma unroll
            for (int nt = 0; nt < 4; nt++)
                acc[mt][nt] = __builtin_amdgcn_mfma_f32_16x16x32_f16(
                    af[mt], bf[nt], acc[mt][nt], 0, 0, 0);
    }
#pragma unroll
    for (int nt = 0; nt < 4; nt++) {
        const int col = cb * 128 + wn * 64 + nt * 16 + l16;
        const float bv = bias[col];
#pragma unroll
        for (int mt = 0; mt < 4; mt++) {
#pragma unroll
            for (int r = 0; r < 4; r++) {
                const int row = rb * 128 + wm * 64 + mt * 16 + quad * 4 + r;
                float v = acc[mt][nt][r] + bv;
                if constexpr (EPI == 0) v = gelu_exact(v);
                if constexpr (EPI == 1) v = fmaxf(v, 0.0f);
                out[(size_t)row * Mout + col] = (f16)v;
            }
        }
    }
}

// ---- k_g2d: dual 128-tile GEMM, bias+resid+BN stats, Mout=128. Grid (256,2):
// cb=0: gine2 (KD=256), cb=1: attn_out (KD=128). Stats rows = 256.
__global__ __launch_bounds__(256) void k_g2d(
    const f16* __restrict__ A0, const f16* __restrict__ Bt0,
    const float* __restrict__ bias0,
    const f16* __restrict__ A1, const f16* __restrict__ Bt1,
    const float* __restrict__ bias1,
    const f16* __restrict__ resid,
    f16* __restrict__ out0, f16* __restrict__ out1,
    float* __restrict__ stats0, float* __restrict__ stats1)
{
    __shared__ __align__(16) f16 Sm[4096 * 8];
    __shared__ float sscr[4][2][64];
    f16* As = Sm;
    f16* Bs = Sm + 2048 * 8;
    const int tid = threadIdx.x;
    const int lane = tid & 63, wid = tid >> 6;
    const int quad = lane >> 4, l16 = lane & 15;
    const int wm = wid >> 1, wn = wid & 1;
    const int rb = blockIdx.x, cb = blockIdx.y;
    const int arow0 = rb * 128;
    const f16* A  = cb ? A1 : A0;
    const f16* Bt = cb ? Bt1 : Bt0;
    const float* bias = cb ? bias1 : bias0;
    f16* out = cb ? out1 : out0;
    float* stats = cb ? stats1 : stats0;
    const int KD = cb ? 128 : 256;
    const int npass = KD >> 7;
    f32x4 acc[4][4];
#pragma unroll
    for (int i = 0; i < 4; i++)
#pragma unroll
        for (int j = 0; j < 4; j++) acc[i][j] = {0.f, 0.f, 0.f, 0.f};
    const int ra0 = wm * 64 + l16, rb0 = wn * 64 + l16;
    for (int p = 0; p < npass; ++p) {
        if (p) __syncthreads();
#pragma unroll
        for (int i = 0; i < 8; i++) {
            int s = i * 256 + wid * 64 + lane;
            int r = s >> 4, cg = (s & 15) ^ (r & 7);
            gload_lds(A + (size_t)(arow0 + r) * KD + p * 128 + cg * 8,
                      As + (size_t)(i * 256 + wid * 64) * 8);
        }
#pragma unroll
        for (int i = 0; i < 8; i++) {
            int s = i * 256 + wid * 64 + lane;
            int r = s >> 4, cg = (s & 15) ^ (r & 7);
            gload_lds(Bt + (size_t)r * KD + p * 128 + cg * 8,
                      Bs + (size_t)(i * 256 + wid * 64) * 8);
        }
        __syncthreads();
#pragma unroll
        for (int kc = 0; kc < 4; ++kc) {
            f16x8 af[4], bf[4];
#pragma unroll
            for (int mt = 0; mt < 4; mt++) {
                int r = ra0 + mt * 16;
                af[mt] = *(const f16x8*)(As + (size_t)(r * 16 + ((kc * 4 + quad) ^ (r & 7))) * 8);
            }
#pragma unroll
            for (int nt = 0; nt < 4; nt++) {
                int r = rb0 + nt * 16;
                bf[nt] = *(const f16x8*)(Bs + (size_t)(r * 16 + ((kc * 4 + quad) ^ (r & 7))) * 8);
            }
#pragma unroll
            for (int mt = 0; mt < 4; mt++)
#pragma unroll
                for (int nt = 0; nt < 4; nt++)
                    acc[mt][nt] = __builtin_amdgcn_mfma_f32_16x16x32_f16(
                        af[mt], bf[nt], acc[mt][nt], 0, 0, 0);
        }
    }
    float ssum[4] = {0, 0, 0, 0}, ssq[4] = {0, 0, 0, 0};
#pragma unroll
    for (int nt = 0; nt < 4; nt++) {
        const int col = wn * 64 + nt * 16 + l16;
        const float bv = bias[col];
#pragma unroll
        for (int mt = 0; mt < 4; mt++) {
#pragma unroll
            for (int r = 0; r < 4; r++) {
                const int row = rb * 128 + wm * 64 + mt * 16 + quad * 4 + r;
                float v = acc[mt][nt][r] + bv;
                v += (float)resid[(size_t)row * 128 + col];
                ssum[nt] += v;
                ssq[nt] += v * v;
                out[(size_t)row * 128 + col] = (f16)v;
            }
        }
    }
#pragma unroll
    for (int nt = 0; nt < 4; nt++) {
        float s = ssum[nt], q = ssq[nt];
        s += __shfl_xor(s, 16); s += __shfl_xor(s, 32);
        q += __shfl_xor(q, 16); q += __shfl_xor(q, 32);
        if (lane < 16) {
            sscr[wid][0][nt * 16 + lane] = s;
            sscr[wid][1][nt * 16 + lane] = q;
        }
    }
    __syncthreads();
    if (tid < 128) {
        int c = tid, wnc = c >> 6, jj = c & 63;
        stats[(size_t)rb * 256 + c] = sscr[wnc][0][jj] + sscr[wnc + 2][0][jj];
        stats[(size_t)rb * 256 + 128 + c] = sscr[wnc][1][jj] + sscr[wnc + 2][1][jj];
    }
}

// ---- k_g2s: 64-tile dual-capable GEMM with stats (kept for mlp2, grid 512x1:
// 512 blocks at y=1 keeps 2+ blocks/CU where a 128-tile would give 1/CU).
__global__ __launch_bounds__(256) void k_g2s(
    const f16* __restrict__ A0, const f16* __restrict__ Bt0,
    const float* __restrict__ bias0,
    const f16* __restrict__ resid,
    f16* __restrict__ out0, float* __restrict__ stats0)
{
    __shared__ __align__(16) f16 Sm[3072 * 8];
    __shared__ float sscr[4][2][64];
    f16* As = Sm;
    f16* Bs = Sm + 1024 * 8;
    const int tid = threadIdx.x;
    const int lane = tid & 63, wid = tid >> 6;
    const int quad = lane >> 4, l16 = lane & 15;
    const int wm = wid >> 1, wn = wid & 1;
    const int rb = blockIdx.x;
    const int arow0 = rb * 64;
    const int KD = 256;
    f32x4 acc[2][4];
#pragma unroll
    for (int i = 0; i < 2; i++)
#pragma unroll
        for (int j = 0; j < 4; j++) acc[i][j] = {0.f, 0.f, 0.f, 0.f};
    const int ra0 = wm * 32 + l16, rb0 = wn * 64 + l16;
    for (int p = 0; p < 2; ++p) {
        if (p) __syncthreads();
#pragma unroll
        for (int i = 0; i < 4; i++) {
            int s = i * 256 + wid * 64 + lane;
            int r = s >> 4, cg = (s & 15) ^ (r & 7);
            gload_lds(A0 + (size_t)(arow0 + r) * KD + p * 128 + cg * 8,
                      As + (size_t)(i * 256 + wid * 64) * 8);
        }
#pragma unroll
        for (int i = 0; i < 8; i++) {
            int s = i * 256 + wid * 64 + lane;
            int r = s >> 4, cg = (s & 15) ^ (r & 7);
            gload_lds(Bt0 + (size_t)r * KD + p * 128 + cg * 8,
                      Bs + (size_t)(i * 256 + wid * 64) * 8);
        }
        __syncthreads();
#pragma unroll
        for (int kc = 0; kc < 4; ++kc) {
            f16x8 af[2], bf[4];
#pragma unroll
            for (int mt = 0; mt < 2; mt++) {
                int r = ra0 + mt * 16;
                af[mt] = *(const f16x8*)(As + (size_t)(r * 16 + ((kc * 4 + quad) ^ (r & 7))) * 8);
            }
#pragma unroll
            for (int nt = 0; nt < 4; nt++) {
                int r = rb0 + nt * 16;
                bf[nt] = *(const f16x8*)(Bs + (size_t)(r * 16 + ((kc * 4 + quad) ^ (r & 7))) * 8);
            }
#pragma unroll
            for (int mt = 0; mt < 2; mt++)
#pragma unroll
                for (int nt = 0; nt < 4; nt++)
                    acc[mt][nt] = __builtin_amdgcn_mfma_f32_16x16x32_f16(
                        af[mt], bf[nt], acc[mt][nt], 0, 0, 0);
        }
    }
    float ssum[4] = {0, 0, 0, 0}, ssq[4] = {0, 0, 0, 0};
#pragma unroll
    for (int nt = 0; nt < 4; nt++) {
        const int col = wn * 64 + nt * 16 + l16;
        const float bv = bias0[col];
#pragma unroll
        for (int mt = 0; mt < 2; mt++) {
#pragma unroll
            for (int r = 0; r < 4; r++) {
                const int row = rb * 64 + wm * 32 + mt * 16 + quad * 4 + r;
                float v = acc[mt][nt][r] + bv;
                v += (float)resid[(size_t)row * 128 + col];
                ssum[nt] += v;
                ssq[nt] += v * v;
                out0[(size_t)row * 128 + col] = (f16)v;
            }
        }
    }
#pragma unroll
    for (int nt = 0; nt < 4; nt++) {
        float s = ssum[nt], q = ssq[nt];
        s += __shfl_xor(s, 16); s += __shfl_xor(s, 32);
        q += __shfl_xor(q, 16); q += __shfl_xor(q, 32);
        if (lane < 16) {
            sscr[wid][0][nt * 16 + lane] = s;
            sscr[wid][1][nt * 16 + lane] = q;
        }
    }
    __syncthreads();
    if (tid < 128) {
        int c = tid, wnc = c >> 6, jj = c & 63;
        stats0[(size_t)rb * 256 + c] = sscr[wnc][0][jj] + sscr[wnc + 2][0][jj];
        stats0[(size_t)rb * 256 + 128 + c] = sscr[wnc][1][jj] + sscr[wnc + 2][1][jj];
    }
}

// ---------------------------------------------------------------------------
// BN finalize: 1024 threads, 8 segments of nb/8 blocks; grid 1 or 2 (A, B)
// ---------------------------------------------------------------------------
__global__ __launch_bounds__(1024) void k_fin(
    const float* __restrict__ sA, const float* __restrict__ sB,
    const float* __restrict__ g1, const float* __restrict__ b1,
    const float* __restrict__ g2, const float* __restrict__ b2,
    float* __restrict__ o1, float* __restrict__ o2, int nb)
{
    __shared__ float rS[8][128], rQ[8][128];
    const float* s = blockIdx.x ? sB : sA;
    const float* g = blockIdx.x ? g2 : g1;
    const float* bb = blockIdx.x ? b2 : b1;
    float* o = blockIdx.x ? o2 : o1;
    const int c = threadIdx.x & 127, seg = threadIdx.x >> 7;
    const int per = nb >> 3;
    float S = 0, Q = 0;
    for (int b = seg * per; b < seg * per + per; b++) {
        S += s[b * 256 + c];
        Q += s[b * 256 + 128 + c];
    }
    rS[seg][c] = S; rQ[seg][c] = Q;
    __syncthreads();
    if (threadIdx.x < 128) {
        float Ss = 0, Qs = 0;
#pragma unroll
        for (int k = 0; k < 8; k++) { Ss += rS[k][c]; Qs += rQ[k][c]; }
        float mean = Ss * (1.0f / 32768.0f);
        float var = Qs * (1.0f / 32768.0f) - mean * mean;
        float rstd = rsqrtf(var + 1e-5f);
        float scv = g[c] * rstd;
        o[c] = scv;
        o[128 + c] = bb[c] - mean * scv;
    }
}

// h = bn3(t3)
__global__ __launch_bounds__(256) void k_bn3(const f16* __restrict__ t3,
    const float* __restrict__ s3, f16* __restrict__ h16)
{
    int i = blockIdx.x * 256 + threadIdx.x;
    int n = i >> 6, c2 = (i & 63) * 2;
    f16x2 a = *(const f16x2*)(t3 + (size_t)n * 128 + c2);
    f16x2 z;
    z[0] = (f16)((float)a[0] * s3[c2] + s3[128 + c2]);
    z[1] = (f16)((float)a[1] * s3[c2 + 1] + s3[129 + c2]);
    *(f16x2*)(h16 + (size_t)n * 128 + c2) = z;
}

// ---------------------------------------------------------------------------
// Attention v5: single-pass fixed-shift softmax (scores structurally small),
// S^T tiles, linear conflict-free P layout, Ks pitch 36, 4 blocks/CU,
// XCD swizzle gh = blk & 255. qb may alias o.
// ---------------------------------------------------------------------------
__global__ __launch_bounds__(256) void k_attn(const f16* __restrict__ qb,
    const f16* __restrict__ kb, const f16* __restrict__ vt, f16* __restrict__ o)
{
    __shared__ __align__(16) f16 Ks[512 * 36];
    __shared__ __align__(16) f16 Ps[4][512];     // per wave: [hf][lane*4]
    const int tid = threadIdx.x;
    const int lane = tid & 63, wid = tid >> 6;
    const int quad = lane >> 4, l16 = lane & 15;
    const int blk = blockIdx.x;
    const int gh = blk & 255, qc = blk >> 8;     // XCD = gh % 8
    const int g = gh >> 2, h = gh & 3;
#pragma unroll
    for (int i = 0; i < 8; i++) {
        int j = i * 256 + tid;
        int n = j >> 2, c4 = j & 3;
        *(uint4*)(Ks + n * 36 + c4 * 8) =
            *(const uint4*)(kb + (size_t)(g * 512 + n) * 128 + h * 32 + c4 * 8);
    }
    const int node = g * 512 + qc * 64 + wid * 16 + l16;
    f16x8 aq = *(const f16x8*)(qb + (size_t)node * 128 + h * 32 + quad * 8);
    __syncthreads();
    const f32x4 zero = {0.f, 0.f, 0.f, 0.f};
    const float cexp = 0.17677669529663689f * 1.44269504088896341f; // scale*log2e
    float lsum = 0.f;
    f32x4 o0 = {0.f, 0.f, 0.f, 0.f}, o1 = {0.f, 0.f, 0.f, 0.f};
    f16* pp = &Ps[wid][0];
    const f16* vbase = vt + (size_t)gh * 32 * 512;
    const int roff = quad * 128;                 // A-frag read offset (halfs)
    for (int ch = 0; ch < 16; ++ch) {
        f16x8 ak0 = *(const f16x8*)(Ks + ((2 * ch) * 16 + l16) * 36 + quad * 8);
        f16x8 ak1 = *(const f16x8*)(Ks + ((2 * ch + 1) * 16 + l16) * 36 + quad * 8);
        f32x4 s0 = __builtin_amdgcn_mfma_f32_16x16x32_f16(ak0, aq, zero, 0, 0, 0);
        f32x4 s1 = __builtin_amdgcn_mfma_f32_16x16x32_f16(ak1, aq, zero, 0, 0, 0);
        f16x4 p0, p1;
#pragma unroll
        for (int r = 0; r < 4; r++) {
            float e0 = exp2f(s0[r] * cexp);
            float e1 = exp2f(s1[r] * cexp);
            lsum += e0 + e1;
            p0[r] = (f16)e0; p1[r] = (f16)e1;
        }
        *(f16x4*)(pp + lane * 4) = p0;           // linear: conflict-free
        *(f16x4*)(pp + 256 + lane * 4) = p1;
        f16x4 a_lo = *(const f16x4*)(pp + roff + l16 * 4);
        f16x4 a_hi = *(const f16x4*)(pp + roff + 64 + l16 * 4);
        f16x8 ap;
#pragma unroll
        for (int i2 = 0; i2 < 4; i2++) { ap[i2] = a_lo[i2]; ap[i2 + 4] = a_hi[i2]; }
        f16x8 bv0 = *(const f16x8*)(vbase + (size_t)l16 * 512 + ch * 32 + quad * 8);
        f16x8 bv1 = *(const f16x8*)(vbase + (size_t)(16 + l16) * 512 + ch * 32 + quad * 8);
        o0 = __builtin_amdgcn_mfma_f32_16x16x32_f16(ap, bv0, o0, 0, 0, 0);
        o1 = __builtin_amdgcn_mfma_f32_16x16x32_f16(ap, bv1, o1, 0, 0, 0);
    }
    lsum += __shfl_xor(lsum, 16);
    lsum += __shfl_xor(lsum, 32);
    const float linv = 1.0f / lsum;              // per q = l16
#pragma unroll
    for (int r = 0; r < 4; r++) {
        float li = __shfl(linv, quad * 4 + r);
        int nrow = g * 512 + qc * 64 + wid * 16 + quad * 4 + r;
        o[(size_t)nrow * 128 + h * 32 + l16] = (f16)(o0[r] * li);
        o[(size_t)nrow * 128 + h * 32 + 16 + l16] = (f16)(o1[r] * li);
    }
}

// ---------------------------------------------------------------------------
// Pool (mean||max per graph) + LayerNorm + head MLP. One block per graph.
// ---------------------------------------------------------------------------
__global__ __launch_bounds__(256) void k_pool(const f16* __restrict__ h16,
    const float* __restrict__ ln_g, const float* __restrict__ ln_b,
    const float* __restrict__ w1, const float* __restrict__ b1,
    const float* __restrict__ w2, const float* __restrict__ b2,
    float* __restrict__ outp)
{
    __shared__ float ssum[4][128], smax[4][128];
    __shared__ float gl[256];
    __shared__ float red[256];
    __shared__ float hid[128];
    __shared__ float stat[2];
    const int tid = threadIdx.x, lane = tid & 63, wid = tid >> 6;
    const int g = blockIdx.x;
    const int c2 = lane * 2;
    float s0 = 0, s1 = 0, m0 = -1e30f, m1 = -1e30f;
    for (int i = 0; i < 128; i++) {
        int n = g * 512 + i * 4 + wid;
        f16x2 hv = *(const f16x2*)(h16 + (size_t)n * 128 + c2);
        float v0 = (float)hv[0], v1 = (float)hv[1];
        s0 += v0; s1 += v1;
        m0 = fmaxf(m0, v0); m1 = fmaxf(m1, v1);
    }
    ssum[wid][c2] = s0; ssum[wid][c2 + 1] = s1;
    smax[wid][c2] = m0; smax[wid][c2 + 1] = m1;
    __syncthreads();
    if (tid < 128) {
        float S = ssum[0][tid] + ssum[1][tid] + ssum[2][tid] + ssum[3][tid];
        float M = fmaxf(fmaxf(smax[0][tid], smax[1][tid]),
                        fmaxf(smax[2][tid], smax[3][tid]));
        gl[tid] = S * (1.0f / 512.0f);
        gl[128 + tid] = M;
    }
    __syncthreads();
    float v = gl[tid];
    red[tid] = v;
    __syncthreads();
    for (int off = 128; off > 0; off >>= 1) {
        if (tid < off) red[tid] += red[tid + off];
        __syncthreads();
    }
    if (tid == 0) stat[0] = red[0] * (1.0f / 256.0f);
    __syncthreads();
    float mu = stat[0];
    red[tid] = (v - mu) * (v - mu);
    __syncthreads();
    for (int off = 128; off > 0; off >>= 1) {
        if (tid < off) red[tid] += red[tid + off];
        __syncthreads();
    }
    if (tid == 0) stat[1] = rsqrtf(red[0] * (1.0f / 256.0f) + 1e-5f);
    __syncthreads();
    float gn = (v - mu) * stat[1] * ln_g[tid] + ln_b[tid];
    __syncthreads();
    gl[tid] = gn;
    __syncthreads();
    if (tid < 128) {
        float a = b1[tid];
        for (int k = 0; k < 256; k++) a += gl[k] * w1[k * 128 + tid];
        hid[tid] = gelu_exact(a);
    }
    __syncthreads();
    if (tid < 64) {
        float a = hid[tid] * w2[tid] + hid[tid + 64] * w2[tid + 64];
        a += __shfl_xor(a, 32); a += __shfl_xor(a, 16); a += __shfl_xor(a, 8);
        a += __shfl_xor(a, 4); a += __shfl_xor(a, 2); a += __shfl_xor(a, 1);
        if (tid == 0) outp[g] = a + b2[0];
    }
}

// ---------------------------------------------------------------------------
extern "C" void kernel_launch(void* const* d_in, const int* in_sizes, int n_in,
                              void* d_out, int out_size, void* d_ws, size_t ws_size,
                              hipStream_t stream)
{
    const float* x          = (const float*)d_in[0];
    const float* edge_attr  = (const float*)d_in[1];
    const int*   ei         = (const int*)d_in[2];
    const float* np_w       = (const float*)d_in[4];
    const float* np_b       = (const float*)d_in[5];
    const float* ep_w       = (const float*)d_in[6];
    const float* ep_b       = (const float*)d_in[7];
    const float* eps        = (const float*)d_in[8];
    const float* gine_w1    = (const float*)d_in[9];
    const float* gine_b1    = (const float*)d_in[10];
    const float* gine_w2    = (const float*)d_in[11];
    const float* gine_b2    = (const float*)d_in[12];
    const float* attn_in_w  = (const float*)d_in[13];
    const float* attn_in_b  = (const float*)d_in[14];
    const float* attn_out_w = (const float*)d_in[15];
    const float* attn_out_b = (const float*)d_in[16];
    const float* bn1_g      = (const float*)d_in[17];
    const float* bn1_b      = (const float*)d_in[18];
    const float* bn2_g      = (const float*)d_in[19];
    const float* bn2_b      = (const float*)d_in[20];
    const float* bn3_g      = (const float*)d_in[21];
    const float* bn3_b      = (const float*)d_in[22];
    const float* mlp_w1     = (const float*)d_in[23];
    const float* mlp_b1     = (const float*)d_in[24];
    const float* mlp_w2     = (const float*)d_in[25];
    const float* mlp_b2     = (const float*)d_in[26];
    const float* ln_g       = (const float*)d_in[27];
    const float* ln_b       = (const float*)d_in[28];
    const float* head_w1    = (const float*)d_in[29];
    const float* head_b1    = (const float*)d_in[30];
    const float* head_w2    = (const float*)d_in[31];
    const float* head_b2    = (const float*)d_in[32];

    char* ws = (char*)d_ws;
    size_t off = 0;
    auto alloc = [&](size_t bytes) {
        void* p = ws + off;
        off += (bytes + 255) & ~(size_t)255;
        return p;
    };
    f16*  h16    = (f16*)alloc((size_t)N_ * 128 * 2);
    f16*  zin    = (f16*)alloc((size_t)N_ * 128 * 2);   // alias: t3
    f16*  tloc   = (f16*)alloc((size_t)N_ * 128 * 2);   // alias: vt (dead at qkv)
    f16*  tattn  = (f16*)alloc((size_t)N_ * 128 * 2);
    f16*  out16  = (f16*)alloc((size_t)N_ * 128 * 2);   // alias: kbuf
    f16*  o16    = (f16*)alloc((size_t)N_ * 128 * 2);   // alias: qbuf
    f16*  u16    = (f16*)alloc((size_t)N_ * 256 * 2);   // live until k_g2d cb=0
    float* statsA = (float*)alloc(512 * 256 * 4);
    float* statsB = (float*)alloc(512 * 256 * 4);
    float* scsh1  = (float*)alloc(256 * 4);
    float* scsh2  = (float*)alloc(256 * 4);
    float* scsh3  = (float*)alloc(256 * 4);
    int*  rowp   = (int*)alloc((N_ + 1) * 4);
    int*  counts = (int*)alloc(N_ * 4);
    int*  cursor = (int*)alloc(N_ * 4);
    int*  srcp   = (int*)alloc((size_t)E_ * 4);
    int*  eidp   = (int*)alloc((size_t)E_ * 4);
    f16*  g1t    = (f16*)alloc((size_t)L_ * 32768 * 2);
    f16*  g2t    = (f16*)alloc((size_t)L_ * 32768 * 2);
    f16*  m1t    = (f16*)alloc((size_t)L_ * 32768 * 2);
    f16*  m2t    = (f16*)alloc((size_t)L_ * 32768 * 2);
    f16*  ait    = (f16*)alloc((size_t)L_ * 49152 * 2);
    f16*  aot    = (f16*)alloc((size_t)L_ * 16384 * 2);
    f16*  e16p   = (f16*)alloc((size_t)E_ * 128 * 2);   // 134 MB, allocated last
    f16*  qbuf = o16;    // attn reads q into regs before writing o (safe alias)
    f16*  kbuf = out16;  // dead between mlp2 consumption and mlp1 aout write
    f16*  vt   = tloc;   // dead between mlp1 consumption and k_g2d write

    dim3 B(256);
    k_prep<<<dim3(3072), B, 0, stream>>>(gine_w1, gine_w2, mlp_w1, mlp_w2,
                                         attn_in_w, attn_out_w,
                                         g1t, g2t, m1t, m2t, ait, aot);
    k_h0<<<dim3(8192), B, 0, stream>>>(x, np_w, np_b, h16);
    k_zero2<<<dim3(128), B, 0, stream>>>(counts, cursor);
    k_count<<<dim3(2048), B, 0, stream>>>(ei, counts);
    k_scan<<<dim3(1), dim3(1024), 0, stream>>>(counts, rowp);
    k_fill<<<dim3(2048), B, 0, stream>>>(ei, rowp, cursor, srcp, eidp);
    k_edge<<<dim3(2048), B, 0, stream>>>(edge_attr, ep_w, ep_b, eidp, e16p);

    const f16* nf = (const f16*)nullptr;
    const float* nff = (const float*)nullptr;
    for (int l = 0; l < L_; l++) {
        k_aggr<<<dim3(8192), B, 0, stream>>>(h16, e16p, srcp, rowp, eps, l, zin);
        k_gq<<<dim3(256, 5), B, 0, stream>>>(
            zin, g1t + l * 32768, gine_b1 + l * 256, u16,
            h16, ait + l * 49152, attn_in_b + l * 384, qbuf, kbuf, vt);
        k_attn<<<dim3(2048), B, 0, stream>>>(qbuf, kbuf, vt, o16);
        k_g2d<<<dim3(256, 2), B, 0, stream>>>(
            u16, g2t + l * 32768, gine_b2 + l * 128,
            o16, aot + l * 16384, attn_out_b + l * 128,
            h16, tloc, tattn, statsA, statsB);
        k_fin<<<dim3(2), dim3(1024), 0, stream>>>(
            statsA, statsB, bn1_g + l * 128, bn1_b + l * 128,
            bn2_g + l * 128, bn2_b + l * 128, scsh1, scsh2, 256);
        k_g128<1, true><<<dim3(256, 2), B, 0, stream>>>(
            nf, m1t + l * 32768, mlp_b1 + l * 256, tloc, tattn, scsh1, scsh2,
            u16, out16, 256);
        k_g2s<<<dim3(512, 1), B, 0, stream>>>(
            u16, m2t + l * 32768, mlp_b2 + l * 128,
            out16, zin, statsA);
        k_fin<<<dim3(1), dim3(1024), 0, stream>>>(
            statsA, statsA, bn3_g + l * 128, bn3_b + l * 128,
            bn3_g + l * 128, bn3_b + l * 128, scsh3, scsh3, 512);
        k_bn3<<<dim3(8192), B, 0, stream>>>(zin, scsh3, h16);
    }
    k_pool<<<dim3(64), B, 0, stream>>>(h16, ln_g, ln_b, head_w1, head_b1,
                                       head_w2, head_b2, (float*)d_out);
}

// Round 11
// 910.955 us; speedup vs baseline: 1.0826x; 1.0826x over previous
//
#include <hip/hip_runtime.h>
#include <math.h>

typedef _Float16 f16;
typedef _Float16 f16x2 __attribute__((ext_vector_type(2)));
typedef _Float16 f16x4 __attribute__((ext_vector_type(4)));
typedef _Float16 f16x8 __attribute__((ext_vector_type(8)));
typedef float f32x4 __attribute__((ext_vector_type(4)));

#define G_ 64
#define NP_ 512
#define N_ 32768
#define E_ 524288
#define C_ 128
#define H_ 4
#define HD_ 32
#define L_ 4

static __device__ __forceinline__ float gelu_exact(float x) {
    return 0.5f * x * (1.0f + erff(x * 0.70710678118654752f));
}

// async global->LDS, 16 B per lane; LDS dst = wave-uniform base + lane*16
static __device__ __forceinline__ void gload_lds(const f16* g, f16* l) {
    __builtin_amdgcn_global_load_lds(
        (const __attribute__((address_space(1))) void*)g,
        (__attribute__((address_space(3))) void*)l, 16, 0, 0);
}

// ---------------------------------------------------------------------------
// Weight prep: transpose gine/mlp weights to Bt=[M][K] layout, cast all to f16
// ---------------------------------------------------------------------------
__global__ __launch_bounds__(256) void k_prep(
    const float* __restrict__ g1, const float* __restrict__ g2,
    const float* __restrict__ m1, const float* __restrict__ m2,
    const float* __restrict__ ai, const float* __restrict__ ao,
    f16* __restrict__ g1t, f16* __restrict__ g2t,
    f16* __restrict__ m1t, f16* __restrict__ m2t,
    f16* __restrict__ ait, f16* __restrict__ aot)
{
    int i = blockIdx.x * 256 + threadIdx.x;
    if (i < 131072) {                       // gine_w1 [l][128][256] -> [l][256][128]
        int l = i >> 15, r = i & 32767;
        int k = r >> 8, m = r & 255;
        g1t[l * 32768 + m * 128 + k] = (f16)g1[i];
    } else if (i < 262144) {                // gine_w2 [l][256][128] -> [l][128][256]
        int j = i - 131072;
        int l = j >> 15, r = j & 32767;
        int k = r >> 7, m = r & 127;
        g2t[l * 32768 + m * 256 + k] = (f16)g2[j];
    } else if (i < 393216) {                // mlp_w1 like gine_w1
        int j = i - 262144;
        int l = j >> 15, r = j & 32767;
        int k = r >> 8, m = r & 255;
        m1t[l * 32768 + m * 128 + k] = (f16)m1[j];
    } else if (i < 524288) {                // mlp_w2 like gine_w2
        int j = i - 393216;
        int l = j >> 15, r = j & 32767;
        int k = r >> 7, m = r & 127;
        m2t[l * 32768 + m * 256 + k] = (f16)m2[j];
    } else if (i < 720896) {                // attn_in_w [l][384][128]: already Bt, cast
        int j = i - 524288;
        ait[j] = (f16)ai[j];
    } else if (i < 786432) {                // attn_out_w [l][128][128]: already Bt, cast
        int j = i - 720896;
        aot[j] = (f16)ao[j];
    }
}

// ---------------------------------------------------------------------------
// h0 = x @ np_w + np_b   (wave per node, 2 channels per lane)
// ---------------------------------------------------------------------------
__global__ __launch_bounds__(256) void k_h0(const float* __restrict__ x,
    const float* __restrict__ w, const float* __restrict__ b,
    f16* __restrict__ h16)
{
    const int tid = threadIdx.x;
    const int lane = tid & 63, wid = tid >> 6;
    const int node = blockIdx.x * 4 + wid;
    const int c2 = lane * 2;
    float a0 = b[c2], a1 = b[c2 + 1];
    const float* xr = x + (size_t)node * 32;
#pragma unroll
    for (int k = 0; k < 32; k++) {
        float xv = xr[k];
        a0 += xv * w[k * 128 + c2];
        a1 += xv * w[k * 128 + c2 + 1];
    }
    f16x2 z; z[0] = (f16)a0; z[1] = (f16)a1;
    *(f16x2*)(h16 + (size_t)node * 128 + c2) = z;
}

// ---------------------------------------------------------------------------
// CSR build (counting sort of edges by dst) — rebuilt every call
// ---------------------------------------------------------------------------
__global__ void k_zero2(int* a, int* b) {
    int i = blockIdx.x * 256 + threadIdx.x;
    a[i] = 0; b[i] = 0;
}
__global__ void k_count(const int* __restrict__ ei, int* __restrict__ counts) {
    int e = blockIdx.x * 256 + threadIdx.x;
    atomicAdd(&counts[ei[E_ + e]], 1);
}
__global__ __launch_bounds__(1024) void k_scan(const int* __restrict__ counts,
                                               int* __restrict__ rowp)
{
    __shared__ int part[1024];
    const int t = threadIdx.x;
    int s = 0;
#pragma unroll
    for (int i = 0; i < 32; i++) s += counts[t * 32 + i];
    part[t] = s;
    __syncthreads();
    for (int off = 1; off < 1024; off <<= 1) {
        int u = (t >= off) ? part[t - off] : 0;
        __syncthreads();
        part[t] += u;
        __syncthreads();
    }
    int run = part[t] - s;  // exclusive prefix of this chunk
    for (int i = 0; i < 32; i++) {
        int c = counts[t * 32 + i];
        rowp[t * 32 + i] = run;
        run += c;
    }
    if (t == 1023) rowp[N_] = part[1023];
}
__global__ void k_fill(const int* __restrict__ ei, const int* __restrict__ rowp,
                       int* __restrict__ cursor, int* __restrict__ srcp,
                       int* __restrict__ eidp)
{
    int e = blockIdx.x * 256 + threadIdx.x;
    int d = ei[E_ + e];
    int p = atomicAdd(&cursor[d], 1);
    int pos = rowp[d] + p;
    srcp[pos] = ei[e];
    eidp[pos] = e;
}

// ---------------------------------------------------------------------------
// Edge embedding, materialized ONCE in CSR-sorted order. XCD-swizzled.
// ---------------------------------------------------------------------------
__global__ __launch_bounds__(256) void k_edge(const float* __restrict__ edge_attr,
    const float* __restrict__ epw, const float* __restrict__ epb,
    const int* __restrict__ eidp, f16* __restrict__ e16p)
{
    __shared__ __align__(16) float rows[4][64][16];  // 16 KB, per-wave regions
    const int tid = threadIdx.x;
    const int lane = tid & 63, wid = tid >> 6;
    const int c2 = lane * 2;
    float w0[16], w1[16];
#pragma unroll
    for (int k = 0; k < 16; k++) {
        w0[k] = epw[k * 128 + c2];
        w1[k] = epw[k * 128 + c2 + 1];
    }
    const float b0 = epb[c2], b1 = epb[c2 + 1];
    const int gidx = blockIdx.x & 63, chunk = blockIdx.x >> 6;
    const int base = (gidx * 32 + chunk) * 256 + wid * 64;
    const int eidv = eidp[base + lane];          // one coalesced load: 64 ids
    const int er = lane >> 2, ec = lane & 3;
#pragma unroll
    for (int u = 0; u < 4; u++) {
        int e = __shfl(eidv, u * 16 + er);
        float4 v = *(const float4*)(edge_attr + (size_t)e * 16 + ec * 4);
        *(float4*)(&rows[wid][u * 16 + er][ec * 4]) = v;
    }
    for (int i = 0; i < 64; i++) {
        const float* r = &rows[wid][i][0];       // broadcast reads (free)
        float4 q0 = *(const float4*)(r);
        float4 q1 = *(const float4*)(r + 4);
        float4 q2 = *(const float4*)(r + 8);
        float4 q3 = *(const float4*)(r + 12);
        float e0 = b0, e1 = b1;
        e0 += q0.x*w0[0] + q0.y*w0[1] + q0.z*w0[2] + q0.w*w0[3]
            + q1.x*w0[4] + q1.y*w0[5] + q1.z*w0[6] + q1.w*w0[7]
            + q2.x*w0[8] + q2.y*w0[9] + q2.z*w0[10] + q2.w*w0[11]
            + q3.x*w0[12] + q3.y*w0[13] + q3.z*w0[14] + q3.w*w0[15];
        e1 += q0.x*w1[0] + q0.y*w1[1] + q0.z*w1[2] + q0.w*w1[3]
            + q1.x*w1[4] + q1.y*w1[5] + q1.z*w1[6] + q1.w*w1[7]
            + q2.x*w1[8] + q2.y*w1[9] + q2.z*w1[10] + q2.w*w1[11]
            + q3.x*w1[12] + q3.y*w1[13] + q3.z*w1[14] + q3.w*w1[15];
        f16x2 z; z[0] = (f16)e0; z[1] = (f16)e1;
        *(f16x2*)(e16p + (size_t)(base + i) * 128 + c2) = z;
    }
}

// ---------------------------------------------------------------------------
// GINE aggregation: zin = (1+eps)*h + sum relu(h[src] + e16p[pos])
// Distance-2 software pipeline; XCD-swizzled per graph.
// ---------------------------------------------------------------------------
__global__ __launch_bounds__(256) void k_aggr(const f16* __restrict__ h16,
    const f16* __restrict__ e16p, const int* __restrict__ srcp,
    const int* __restrict__ rowp, const float* __restrict__ eps, int layer,
    f16* __restrict__ zin)
{
    const int tid = threadIdx.x;
    const int lane = tid & 63, wid = tid >> 6;
    const int node = (blockIdx.x & 63) * 512 + (blockIdx.x >> 6) * 4 + wid;
    const int c2 = lane * 2;
    const int r0 = rowp[node], r1 = rowp[node + 1];
    const int deg = r1 - r0;
    const f16x2 hn = *(const f16x2*)(h16 + (size_t)node * 128 + c2);
    float a0 = 0.f, a1 = 0.f;
    if (deg > 0) {
        const int dd = deg < 64 ? deg : 64;
        const int jm = dd - 1;
        const int srcv = srcp[r0 + (lane < jm ? lane : jm)];
        f16x2 h_c, e_c, h_n, e_n;
        {
            int s = __shfl(srcv, 0);
            h_c = *(const f16x2*)(h16 + (size_t)s * 128 + c2);
            e_c = *(const f16x2*)(e16p + (size_t)r0 * 128 + c2);
            int j1 = 1 < jm ? 1 : jm;
            int s1 = __shfl(srcv, j1);
            h_n = *(const f16x2*)(h16 + (size_t)s1 * 128 + c2);
            e_n = *(const f16x2*)(e16p + (size_t)(r0 + j1) * 128 + c2);
        }
        for (int j = 0; j < dd; ++j) {
            int j2 = j + 2 < jm ? j + 2 : jm;
            int s2 = __shfl(srcv, j2);
            f16x2 h_f = *(const f16x2*)(h16 + (size_t)s2 * 128 + c2);
            f16x2 e_f = *(const f16x2*)(e16p + (size_t)(r0 + j2) * 128 + c2);
            a0 += fmaxf((float)e_c[0] + (float)h_c[0], 0.0f);
            a1 += fmaxf((float)e_c[1] + (float)h_c[1], 0.0f);
            h_c = h_n; e_c = e_n; h_n = h_f; e_n = e_f;
        }
        for (int pos = r0 + 64; pos < r1; ++pos) {
            int s = srcp[pos];
            f16x2 ev = *(const f16x2*)(e16p + (size_t)pos * 128 + c2);
            f16x2 hv = *(const f16x2*)(h16 + (size_t)s * 128 + c2);
            a0 += fmaxf((float)ev[0] + (float)hv[0], 0.0f);
            a1 += fmaxf((float)ev[1] + (float)hv[1], 0.0f);
        }
    }
    const float ep = 1.0f + eps[layer];
    f16x2 z;
    z[0] = (f16)(ep * (float)hn[0] + a0);
    z[1] = (f16)(ep * (float)hn[1] + a1);
    *(f16x2*)(zin + (size_t)node * 128 + c2) = z;
}

// ===========================================================================
// GEMM core v2: full-K-slab staging via global_load_lds (width 16) with XOR
// swizzle (LDS chunk (r,c) holds global chunk c^(r&7)). One barrier per
// 128-K pass, 32 MFMAs between. Block = 64x128, 4 waves (2x2). LDS 48 KB
// -> 3 blocks/CU (the sweet spot: round-10's 128^2 tiles at 2 blocks/CU
// regressed; overlap beats per-byte MFMA density at these small K).
// ===========================================================================

// ---- k_gq: merged gine1 + qkv (both KD=128, A differs). Grid (512, 5):
// cb 0-1: u16[.,cb*128..] = gelu(zin @ g1t^T + b) ; cb 2-4: qkv from h16.
__global__ __launch_bounds__(256) void k_gq(
    const f16* __restrict__ zin, const f16* __restrict__ g1t,
    const float* __restrict__ gb1, f16* __restrict__ u16,
    const f16* __restrict__ h16, const f16* __restrict__ ait,
    const float* __restrict__ aib,
    f16* __restrict__ qb, f16* __restrict__ kb, f16* __restrict__ vt)
{
    __shared__ __align__(16) f16 Sm[3072 * 8];
    f16* As = Sm;
    f16* Bs = Sm + 1024 * 8;
    const int tid = threadIdx.x;
    const int lane = tid & 63, wid = tid >> 6;
    const int quad = lane >> 4, l16 = lane & 15;
    const int wm = wid >> 1, wn = wid & 1;
    const int rb = blockIdx.x, cb = blockIdx.y;
    const bool is_qkv = (cb >= 2);
    const int cbl = is_qkv ? (cb - 2) : cb;
    const f16* A  = is_qkv ? h16 : zin;
    const f16* Bt = is_qkv ? ait : g1t;
    const int arow0 = rb * 64, brow0 = cbl * 128;
#pragma unroll
    for (int i = 0; i < 8; i++) {
        int s = i * 256 + wid * 64 + lane;
        int r = s >> 4, cg = (s & 15) ^ (r & 7);
        gload_lds(Bt + (size_t)(brow0 + r) * 128 + cg * 8,
                  Bs + (size_t)(i * 256 + wid * 64) * 8);
    }
#pragma unroll
    for (int i = 0; i < 4; i++) {
        int s = i * 256 + wid * 64 + lane;
        int r = s >> 4, cg = (s & 15) ^ (r & 7);
        gload_lds(A + (size_t)(arow0 + r) * 128 + cg * 8,
                  As + (size_t)(i * 256 + wid * 64) * 8);
    }
    __syncthreads();
    f32x4 acc[2][4];
#pragma unroll
    for (int i = 0; i < 2; i++)
#pragma unroll
        for (int j = 0; j < 4; j++) acc[i][j] = {0.f, 0.f, 0.f, 0.f};
    const int ra0 = wm * 32 + l16, rb0 = wn * 64 + l16;
#pragma unroll
    for (int kc = 0; kc < 4; ++kc) {
        f16x8 af[2], bf[4];
#pragma unroll
        for (int mt = 0; mt < 2; mt++) {
            int r = ra0 + mt * 16;
            af[mt] = *(const f16x8*)(As + (size_t)(r * 16 + ((kc * 4 + quad) ^ (r & 7))) * 8);
        }
#pragma unroll
        for (int nt = 0; nt < 4; nt++) {
            int r = rb0 + nt * 16;
            bf[nt] = *(const f16x8*)(Bs + (size_t)(r * 16 + ((kc * 4 + quad) ^ (r & 7))) * 8);
        }
#pragma unroll
        for (int mt = 0; mt < 2; mt++)
#pragma unroll
            for (int nt = 0; nt < 4; nt++)
                acc[mt][nt] = __builtin_amdgcn_mfma_f32_16x16x32_f16(
                    af[mt], bf[nt], acc[mt][nt], 0, 0, 0);
    }
    if (!is_qkv) {
#pragma unroll
        for (int nt = 0; nt < 4; nt++) {
            const int col = cbl * 128 + wn * 64 + nt * 16 + l16;
            const float bv = gb1[col];
#pragma unroll
            for (int mt = 0; mt < 2; mt++) {
#pragma unroll
                for (int r = 0; r < 4; r++) {
                    const int row = rb * 64 + wm * 32 + mt * 16 + quad * 4 + r;
                    u16[(size_t)row * 256 + col] = (f16)gelu_exact(acc[mt][nt][r] + bv);
                }
            }
        }
    } else if (cbl < 2) {
        f16* outp = cbl ? kb : qb;
#pragma unroll
        for (int nt = 0; nt < 4; nt++) {
            const int col = wn * 64 + nt * 16 + l16;
            const float bv = aib[cbl * 128 + col];
#pragma unroll
            for (int mt = 0; mt < 2; mt++) {
#pragma unroll
                for (int r = 0; r < 4; r++) {
                    const int row = rb * 64 + wm * 32 + mt * 16 + quad * 4 + r;
                    outp[(size_t)row * 128 + col] = (f16)(acc[mt][nt][r] + bv);
                }
            }
        }
    } else {
        const int g = rb >> 3;
#pragma unroll
        for (int nt = 0; nt < 4; nt++) {
            const int coll = wn * 64 + nt * 16 + l16;
            const int h = coll >> 5, d = coll & 31;
            const float bv = aib[256 + coll];
#pragma unroll
            for (int mt = 0; mt < 2; mt++) {
                const int n0 = (rb & 7) * 64 + wm * 32 + mt * 16 + quad * 4;
                f16x4 z;
#pragma unroll
                for (int r = 0; r < 4; r++) z[r] = (f16)(acc[mt][nt][r] + bv);
                *(f16x4*)(vt + ((size_t)((g * 4 + h) * 32 + d)) * 512 + n0) = z;
            }
        }
    }
}

// ---- k_g128: KD=128 single GEMM (used for mlp1 with COMB A-fusion).
// EPI: 0=bias+GELU, 1=bias+ReLU. COMB: A=bn1(r1)+bn2(r2), side-write aout.
template <int EPI, bool COMB>
__global__ __launch_bounds__(256) void k_g128(
    const f16* __restrict__ A, const f16* __restrict__ Bt,
    const float* __restrict__ bias,
    const f16* __restrict__ r1, const f16* __restrict__ r2,
    const float* __restrict__ sc1, const float* __restrict__ sc2,
    f16* __restrict__ out, f16* __restrict__ aout, int Mout)
{
    __shared__ __align__(16) f16 Sm[3072 * 8];       // As 1024 | Bs 2048 chunks
    __shared__ float sca[4][128];
    f16* As = Sm;
    f16* Bs = Sm + 1024 * 8;
    const int tid = threadIdx.x;
    const int lane = tid & 63, wid = tid >> 6;
    const int quad = lane >> 4, l16 = lane & 15;
    const int wm = wid >> 1, wn = wid & 1;
    const int rb = blockIdx.x, cb = blockIdx.y;
    const int arow0 = rb * 64, brow0 = cb * 128;
#pragma unroll
    for (int i = 0; i < 8; i++) {
        int s = i * 256 + wid * 64 + lane;
        int r = s >> 4, cg = (s & 15) ^ (r & 7);
        gload_lds(Bt + (size_t)(brow0 + r) * 128 + cg * 8,
                  Bs + (size_t)(i * 256 + wid * 64) * 8);
    }
    if constexpr (!COMB) {
#pragma unroll
        for (int i = 0; i < 4; i++) {
            int s = i * 256 + wid * 64 + lane;
            int r = s >> 4, cg = (s & 15) ^ (r & 7);
            gload_lds(A + (size_t)(arow0 + r) * 128 + cg * 8,
                      As + (size_t)(i * 256 + wid * 64) * 8);
        }
        __syncthreads();
    } else {
        if (tid < 128) { sca[0][tid] = sc1[tid]; sca[1][tid] = sc1[128 + tid]; }
        else { int c = tid - 128; sca[2][c] = sc2[c]; sca[3][c] = sc2[128 + c]; }
        __syncthreads();
#pragma unroll
        for (int j = 0; j < 4; j++) {
            int s = j * 256 + tid;
            int r = s >> 4, cg = (s & 15) ^ (r & 7);
            size_t off = (size_t)(arow0 + r) * 128 + cg * 8;
            f16x8 x1 = *(const f16x8*)(r1 + off);
            f16x8 x2 = *(const f16x8*)(r2 + off);
            f16x8 zc;
#pragma unroll
            for (int i2 = 0; i2 < 8; i2++) {
                int k = cg * 8 + i2;
                float v = (float)x1[i2] * sca[0][k] + sca[1][k]
                        + (float)x2[i2] * sca[2][k] + sca[3][k];
                zc[i2] = (f16)v;
            }
            *(f16x8*)(As + (size_t)s * 8) = zc;
            if (cb == 0) *(f16x8*)(aout + off) = zc;
        }
        __syncthreads();
    }
    f32x4 acc[2][4];
#pragma unroll
    for (int i = 0; i < 2; i++)
#pragma unroll
        for (int j = 0; j < 4; j++) acc[i][j] = {0.f, 0.f, 0.f, 0.f};
    const int ra0 = wm * 32 + l16, rb0 = wn * 64 + l16;
#pragma unroll
    for (int kc = 0; kc < 4; ++kc) {
        f16x8 af[2], bf[4];
#pragma unroll
        for (int mt = 0; mt < 2; mt++) {
            int r = ra0 + mt * 16;
            af[mt] = *(const f16x8*)(As + (size_t)(r * 16 + ((kc * 4 + quad) ^ (r & 7))) * 8);
        }
#pragma unroll
        for (int nt = 0; nt < 4; nt++) {
            int r = rb0 + nt * 16;
            bf[nt] = *(const f16x8*)(Bs + (size_t)(r * 16 + ((kc * 4 + quad) ^ (r & 7))) * 8);
        }
#pragma unroll
        for (int mt = 0; mt < 2; mt++)
#pragma unroll
            for (int nt = 0; nt < 4; nt++)
                acc[mt][nt] = __builtin_amdgcn_mfma_f32_16x16x32_f16(
                    af[mt], bf[nt], acc[mt][nt], 0, 0, 0);
    }
#pragma unroll
    for (int nt = 0; nt < 4; nt++) {
        const int col = cb * 128 + wn * 64 + nt * 16 + l16;
        const float bv = bias[col];
#pragma unroll
        for (int mt = 0; mt < 2; mt++) {
#pragma unroll
            for (int r = 0; r < 4; r++) {
                const int row = rb * 64 + wm * 32 + mt * 16 + quad * 4 + r;
                float v = acc[mt][nt][r] + bv;
                if constexpr (EPI == 0) v = gelu_exact(v);
                if constexpr (EPI == 1) v = fmaxf(v, 0.0f);
                out[(size_t)row * Mout + col] = (f16)v;
            }
        }
    }
}

// ---- k_g2: dual GEMM, EPI=2 (bias+resid+BN partial stats), Mout=128.
// cb=0: A0/Bt0 (KD=256), cb=1: A1/Bt1 (KD=128). mlp2 uses grid (512,1). ----
__global__ __launch_bounds__(256) void k_g2(
    const f16* __restrict__ A0, const f16* __restrict__ Bt0,
    const float* __restrict__ bias0,
    const f16* __restrict__ A1, const f16* __restrict__ Bt1,
    const float* __restrict__ bias1,
    const f16* __restrict__ resid,
    f16* __restrict__ out0, f16* __restrict__ out1,
    float* __restrict__ stats0, float* __restrict__ stats1)
{
    __shared__ __align__(16) f16 Sm[3072 * 8];
    __shared__ float sscr[4][2][64];
    f16* As = Sm;
    f16* Bs = Sm + 1024 * 8;
    const int tid = threadIdx.x;
    const int lane = tid & 63, wid = tid >> 6;
    const int quad = lane >> 4, l16 = lane & 15;
    const int wm = wid >> 1, wn = wid & 1;
    const int rb = blockIdx.x, cb = blockIdx.y;
    const int arow0 = rb * 64;
    const f16* A  = cb ? A1 : A0;
    const f16* Bt = cb ? Bt1 : Bt0;
    const float* bias = cb ? bias1 : bias0;
    f16* out = cb ? out1 : out0;
    float* stats = cb ? stats1 : stats0;
    const int KD = cb ? 128 : 256;
    const int npass = KD >> 7;
    f32x4 acc[2][4];
#pragma unroll
    for (int i = 0; i < 2; i++)
#pragma unroll
        for (int j = 0; j < 4; j++) acc[i][j] = {0.f, 0.f, 0.f, 0.f};
    const int ra0 = wm * 32 + l16, rb0 = wn * 64 + l16;
    for (int p = 0; p < npass; ++p) {
        if (p) __syncthreads();
#pragma unroll
        for (int i = 0; i < 4; i++) {
            int s = i * 256 + wid * 64 + lane;
            int r = s >> 4, cg = (s & 15) ^ (r & 7);
            gload_lds(A + (size_t)(arow0 + r) * KD + p * 128 + cg * 8,
                      As + (size_t)(i * 256 + wid * 64) * 8);
        }
#pragma unroll
        for (int i = 0; i < 8; i++) {
            int s = i * 256 + wid * 64 + lane;
            int r = s >> 4, cg = (s & 15) ^ (r & 7);
            gload_lds(Bt + (size_t)r * KD + p * 128 + cg * 8,
                      Bs + (size_t)(i * 256 + wid * 64) * 8);
        }
        __syncthreads();
#pragma unroll
        for (int kc = 0; kc < 4; ++kc) {
            f16x8 af[2], bf[4];
#pragma unroll
            for (int mt = 0; mt < 2; mt++) {
                int r = ra0 + mt * 16;
                af[mt] = *(const f16x8*)(As + (size_t)(r * 16 + ((kc * 4 + quad) ^ (r & 7))) * 8);
            }
#pragma unroll
            for (int nt = 0; nt < 4; nt++) {
                int r = rb0 + nt * 16;
                bf[nt] = *(const f16x8*)(Bs + (size_t)(r * 16 + ((kc * 4 + quad) ^ (r & 7))) * 8);
            }
#pragma unroll
            for (int mt = 0; mt < 2; mt++)
#pragma unroll
                for (int nt = 0; nt < 4; nt++)
                    acc[mt][nt] = __builtin_amdgcn_mfma_f32_16x16x32_f16(
                        af[mt], bf[nt], acc[mt][nt], 0, 0, 0);
        }
    }
    float ssum[4] = {0, 0, 0, 0}, ssq[4] = {0, 0, 0, 0};
#pragma unroll
    for (int nt = 0; nt < 4; nt++) {
        const int col = wn * 64 + nt * 16 + l16;
        const float bv = bias[col];
#pragma unroll
        for (int mt = 0; mt < 2; mt++) {
#pragma unroll
            for (int r = 0; r < 4; r++) {
                const int row = rb * 64 + wm * 32 + mt * 16 + quad * 4 + r;
                float v = acc[mt][nt][r] + bv;
                v += (float)resid[(size_t)row * 128 + col];
                ssum[nt] += v;
                ssq[nt] += v * v;
                out[(size_t)row * 128 + col] = (f16)v;
            }
        }
    }
#pragma unroll
    for (int nt = 0; nt < 4; nt++) {
        float s = ssum[nt], q = ssq[nt];
        s += __shfl_xor(s, 16); s += __shfl_xor(s, 32);
        q += __shfl_xor(q, 16); q += __shfl_xor(q, 32);
        if (lane < 16) {
            sscr[wid][0][nt * 16 + lane] = s;
            sscr[wid][1][nt * 16 + lane] = q;
        }
    }
    __syncthreads();
    if (tid < 128) {
        int c = tid, wnc = c >> 6, jj = c & 63;
        stats[(size_t)rb * 256 + c] = sscr[wnc][0][jj] + sscr[wnc + 2][0][jj];
        stats[(size_t)rb * 256 + 128 + c] = sscr[wnc][1][jj] + sscr[wnc + 2][1][jj];
    }
}

// ---------------------------------------------------------------------------
// BN finalize: 1024 threads, 8 segments of 64 blocks; grid 1 or 2 (A then B)
// ---------------------------------------------------------------------------
__global__ __launch_bounds__(1024) void k_fin(
    const float* __restrict__ sA, const float* __restrict__ sB,
    const float* __restrict__ g1, const float* __restrict__ b1,
    const float* __restrict__ g2, const float* __restrict__ b2,
    float* __restrict__ o1, float* __restrict__ o2)
{
    __shared__ float rS[8][128], rQ[8][128];
    const float* s = blockIdx.x ? sB : sA;
    const float* g = blockIdx.x ? g2 : g1;
    const float* bb = blockIdx.x ? b2 : b1;
    float* o = blockIdx.x ? o2 : o1;
    const int c = threadIdx.x & 127, seg = threadIdx.x >> 7;
    float S = 0, Q = 0;
    for (int b = seg * 64; b < seg * 64 + 64; b++) {
        S += s[b * 256 + c];
        Q += s[b * 256 + 128 + c];
    }
    rS[seg][c] = S; rQ[seg][c] = Q;
    __syncthreads();
    if (threadIdx.x < 128) {
        float Ss = 0, Qs = 0;
#pragma unroll
        for (int k = 0; k < 8; k++) { Ss += rS[k][c]; Qs += rQ[k][c]; }
        float mean = Ss * (1.0f / 32768.0f);
        float var = Qs * (1.0f / 32768.0f) - mean * mean;
        float rstd = rsqrtf(var + 1e-5f);
        float scv = g[c] * rstd;
        o[c] = scv;
        o[128 + c] = bb[c] - mean * scv;
    }
}

// h = bn3(t3)
__global__ __launch_bounds__(256) void k_bn3(const f16* __restrict__ t3,
    const float* __restrict__ s3, f16* __restrict__ h16)
{
    int i = blockIdx.x * 256 + threadIdx.x;
    int n = i >> 6, c2 = (i & 63) * 2;
    f16x2 a = *(const f16x2*)(t3 + (size_t)n * 128 + c2);
    f16x2 z;
    z[0] = (f16)((float)a[0] * s3[c2] + s3[128 + c2]);
    z[1] = (f16)((float)a[1] * s3[c2 + 1] + s3[129 + c2]);
    *(f16x2*)(h16 + (size_t)n * 128 + c2) = z;
}

// ---------------------------------------------------------------------------
// Attention v5: SINGLE-PASS fixed-shift softmax (no max pass; softmax is
// shift-invariant and |s|*scale << f16 overflow for BN-normalized inputs).
// S^T tiles (A=K-frag), linear conflict-free P layout, Ks pitch 36,
// LDS 40960 B -> 4 blocks/CU, XCD swizzle gh = blk & 255.
// NOTE: qb and o may be the SAME buffer (q read into regs before o write;
// regions per block are identical and cross-block disjoint).
// ---------------------------------------------------------------------------
__global__ __launch_bounds__(256) void k_attn(const f16* __restrict__ qb,
    const f16* __restrict__ kb, const f16* __restrict__ vt, f16* __restrict__ o)
{
    __shared__ __align__(16) f16 Ks[512 * 36];
    __shared__ __align__(16) f16 Ps[4][512];     // per wave: [hf][lane*4]
    const int tid = threadIdx.x;
    const int lane = tid & 63, wid = tid >> 6;
    const int quad = lane >> 4, l16 = lane & 15;
    const int blk = blockIdx.x;
    const int gh = blk & 255, qc = blk >> 8;     // XCD = gh % 8
    const int g = gh >> 2, h = gh & 3;
#pragma unroll
    for (int i = 0; i < 8; i++) {
        int j = i * 256 + tid;
        int n = j >> 2, c4 = j & 3;
        *(uint4*)(Ks + n * 36 + c4 * 8) =
            *(const uint4*)(kb + (size_t)(g * 512 + n) * 128 + h * 32 + c4 * 8);
    }
    const int node = g * 512 + qc * 64 + wid * 16 + l16;
    f16x8 aq = *(const f16x8*)(qb + (size_t)node * 128 + h * 32 + quad * 8);
    __syncthreads();
    const f32x4 zero = {0.f, 0.f, 0.f, 0.f};
    const float cexp = 0.17677669529663689f * 1.44269504088896341f; // scale*log2e
    float lsum = 0.f;
    f32x4 o0 = {0.f, 0.f, 0.f, 0.f}, o1 = {0.f, 0.f, 0.f, 0.f};
    f16* pp = &Ps[wid][0];
    const f16* vbase = vt + (size_t)gh * 32 * 512;
    const int roff = quad * 128;                 // A-frag read offset (halfs)
    for (int ch = 0; ch < 16; ++ch) {
        f16x8 ak0 = *(const f16x8*)(Ks + ((2 * ch) * 16 + l16) * 36 + quad * 8);
        f16x8 ak1 = *(const f16x8*)(Ks + ((2 * ch + 1) * 16 + l16) * 36 + quad * 8);
        f32x4 s0 = __builtin_amdgcn_mfma_f32_16x16x32_f16(ak0, aq, zero, 0, 0, 0);
        f32x4 s1 = __builtin_amdgcn_mfma_f32_16x16x32_f16(ak1, aq, zero, 0, 0, 0);
        f16x4 p0, p1;
#pragma unroll
        for (int r = 0; r < 4; r++) {
            float e0 = exp2f(s0[r] * cexp);
            float e1 = exp2f(s1[r] * cexp);
            lsum += e0 + e1;
            p0[r] = (f16)e0; p1[r] = (f16)e1;
        }
        *(f16x4*)(pp + lane * 4) = p0;           // linear: conflict-free
        *(f16x4*)(pp + 256 + lane * 4) = p1;
        f16x4 a_lo = *(const f16x4*)(pp + roff + l16 * 4);
        f16x4 a_hi = *(const f16x4*)(pp + roff + 64 + l16 * 4);
        f16x8 ap;
#pragma unroll
        for (int i2 = 0; i2 < 4; i2++) { ap[i2] = a_lo[i2]; ap[i2 + 4] = a_hi[i2]; }
        f16x8 bv0 = *(const f16x8*)(vbase + (size_t)l16 * 512 + ch * 32 + quad * 8);
        f16x8 bv1 = *(const f16x8*)(vbase + (size_t)(16 + l16) * 512 + ch * 32 + quad * 8);
        o0 = __builtin_amdgcn_mfma_f32_16x16x32_f16(ap, bv0, o0, 0, 0, 0);
        o1 = __builtin_amdgcn_mfma_f32_16x16x32_f16(ap, bv1, o1, 0, 0, 0);
    }
    lsum += __shfl_xor(lsum, 16);
    lsum += __shfl_xor(lsum, 32);
    const float linv = 1.0f / lsum;              // per q = l16
#pragma unroll
    for (int r = 0; r < 4; r++) {
        float li = __shfl(linv, quad * 4 + r);
        int nrow = g * 512 + qc * 64 + wid * 16 + quad * 4 + r;
        o[(size_t)nrow * 128 + h * 32 + l16] = (f16)(o0[r] * li);
        o[(size_t)nrow * 128 + h * 32 + 16 + l16] = (f16)(o1[r] * li);
    }
}

// ---------------------------------------------------------------------------
// Pool (mean||max per graph) + LayerNorm + head MLP. One block per graph.
// ---------------------------------------------------------------------------
__global__ __launch_bounds__(256) void k_pool(const f16* __restrict__ h16,
    const float* __restrict__ ln_g, const float* __restrict__ ln_b,
    const float* __restrict__ w1, const float* __restrict__ b1,
    const float* __restrict__ w2, const float* __restrict__ b2,
    float* __restrict__ outp)
{
    __shared__ float ssum[4][128], smax[4][128];
    __shared__ float gl[256];
    __shared__ float red[256];
    __shared__ float hid[128];
    __shared__ float stat[2];
    const int tid = threadIdx.x, lane = tid & 63, wid = tid >> 6;
    const int g = blockIdx.x;
    const int c2 = lane * 2;
    float s0 = 0, s1 = 0, m0 = -1e30f, m1 = -1e30f;
    for (int i = 0; i < 128; i++) {
        int n = g * 512 + i * 4 + wid;
        f16x2 hv = *(const f16x2*)(h16 + (size_t)n * 128 + c2);
        float v0 = (float)hv[0], v1 = (float)hv[1];
        s0 += v0; s1 += v1;
        m0 = fmaxf(m0, v0); m1 = fmaxf(m1, v1);
    }
    ssum[wid][c2] = s0; ssum[wid][c2 + 1] = s1;
    smax[wid][c2] = m0; smax[wid][c2 + 1] = m1;
    __syncthreads();
    if (tid < 128) {
        float S = ssum[0][tid] + ssum[1][tid] + ssum[2][tid] + ssum[3][tid];
        float M = fmaxf(fmaxf(smax[0][tid], smax[1][tid]),
                        fmaxf(smax[2][tid], smax[3][tid]));
        gl[tid] = S * (1.0f / 512.0f);
        gl[128 + tid] = M;
    }
    __syncthreads();
    float v = gl[tid];
    red[tid] = v;
    __syncthreads();
    for (int off = 128; off > 0; off >>= 1) {
        if (tid < off) red[tid] += red[tid + off];
        __syncthreads();
    }
    if (tid == 0) stat[0] = red[0] * (1.0f / 256.0f);
    __syncthreads();
    float mu = stat[0];
    red[tid] = (v - mu) * (v - mu);
    __syncthreads();
    for (int off = 128; off > 0; off >>= 1) {
        if (tid < off) red[tid] += red[tid + off];
        __syncthreads();
    }
    if (tid == 0) stat[1] = rsqrtf(red[0] * (1.0f / 256.0f) + 1e-5f);
    __syncthreads();
    float gn = (v - mu) * stat[1] * ln_g[tid] + ln_b[tid];
    __syncthreads();
    gl[tid] = gn;
    __syncthreads();
    if (tid < 128) {
        float a = b1[tid];
        for (int k = 0; k < 256; k++) a += gl[k] * w1[k * 128 + tid];
        hid[tid] = gelu_exact(a);
    }
    __syncthreads();
    if (tid < 64) {
        float a = hid[tid] * w2[tid] + hid[tid + 64] * w2[tid + 64];
        a += __shfl_xor(a, 32); a += __shfl_xor(a, 16); a += __shfl_xor(a, 8);
        a += __shfl_xor(a, 4); a += __shfl_xor(a, 2); a += __shfl_xor(a, 1);
        if (tid == 0) outp[g] = a + b2[0];
    }
}

// ---------------------------------------------------------------------------
extern "C" void kernel_launch(void* const* d_in, const int* in_sizes, int n_in,
                              void* d_out, int out_size, void* d_ws, size_t ws_size,
                              hipStream_t stream)
{
    const float* x          = (const float*)d_in[0];
    const float* edge_attr  = (const float*)d_in[1];
    const int*   ei         = (const int*)d_in[2];
    const float* np_w       = (const float*)d_in[4];
    const float* np_b       = (const float*)d_in[5];
    const float* ep_w       = (const float*)d_in[6];
    const float* ep_b       = (const float*)d_in[7];
    const float* eps        = (const float*)d_in[8];
    const float* gine_w1    = (const float*)d_in[9];
    const float* gine_b1    = (const float*)d_in[10];
    const float* gine_w2    = (const float*)d_in[11];
    const float* gine_b2    = (const float*)d_in[12];
    const float* attn_in_w  = (const float*)d_in[13];
    const float* attn_in_b  = (const float*)d_in[14];
    const float* attn_out_w = (const float*)d_in[15];
    const float* attn_out_b = (const float*)d_in[16];
    const float* bn1_g      = (const float*)d_in[17];
    const float* bn1_b      = (const float*)d_in[18];
    const float* bn2_g      = (const float*)d_in[19];
    const float* bn2_b      = (const float*)d_in[20];
    const float* bn3_g      = (const float*)d_in[21];
    const float* bn3_b      = (const float*)d_in[22];
    const float* mlp_w1     = (const float*)d_in[23];
    const float* mlp_b1     = (const float*)d_in[24];
    const float* mlp_w2     = (const float*)d_in[25];
    const float* mlp_b2     = (const float*)d_in[26];
    const float* ln_g       = (const float*)d_in[27];
    const float* ln_b       = (const float*)d_in[28];
    const float* head_w1    = (const float*)d_in[29];
    const float* head_b1    = (const float*)d_in[30];
    const float* head_w2    = (const float*)d_in[31];
    const float* head_b2    = (const float*)d_in[32];

    char* ws = (char*)d_ws;
    size_t off = 0;
    auto alloc = [&](size_t bytes) {
        void* p = ws + off;
        off += (bytes + 255) & ~(size_t)255;
        return p;
    };
    f16*  h16    = (f16*)alloc((size_t)N_ * 128 * 2);
    f16*  zin    = (f16*)alloc((size_t)N_ * 128 * 2);   // alias: t3
    f16*  tloc   = (f16*)alloc((size_t)N_ * 128 * 2);   // alias: vt (dead at qkv)
    f16*  tattn  = (f16*)alloc((size_t)N_ * 128 * 2);
    f16*  out16  = (f16*)alloc((size_t)N_ * 128 * 2);   // alias: kbuf
    f16*  o16    = (f16*)alloc((size_t)N_ * 128 * 2);   // alias: qbuf (q read
                                                        //  pre-write in attn)
    f16*  u16    = (f16*)alloc((size_t)N_ * 256 * 2);   // live until k_g2 cb=0
    float* statsA = (float*)alloc(512 * 256 * 4);
    float* statsB = (float*)alloc(512 * 256 * 4);
    float* scsh1  = (float*)alloc(256 * 4);
    float* scsh2  = (float*)alloc(256 * 4);
    float* scsh3  = (float*)alloc(256 * 4);
    int*  rowp   = (int*)alloc((N_ + 1) * 4);
    int*  counts = (int*)alloc(N_ * 4);
    int*  cursor = (int*)alloc(N_ * 4);
    int*  srcp   = (int*)alloc((size_t)E_ * 4);
    int*  eidp   = (int*)alloc((size_t)E_ * 4);
    f16*  g1t    = (f16*)alloc((size_t)L_ * 32768 * 2);
    f16*  g2t    = (f16*)alloc((size_t)L_ * 32768 * 2);
    f16*  m1t    = (f16*)alloc((size_t)L_ * 32768 * 2);
    f16*  m2t    = (f16*)alloc((size_t)L_ * 32768 * 2);
    f16*  ait    = (f16*)alloc((size_t)L_ * 49152 * 2);
    f16*  aot    = (f16*)alloc((size_t)L_ * 16384 * 2);
    f16*  e16p   = (f16*)alloc((size_t)E_ * 128 * 2);   // 134 MB, allocated last
    f16*  qbuf = o16;    // attn reads q into regs before writing o (safe alias)
    f16*  kbuf = out16;  // dead between mlp2 consumption and mlp1 aout write
    f16*  vt   = tloc;   // dead between mlp1 consumption and k_g2 write

    dim3 B(256);
    k_prep<<<dim3(3072), B, 0, stream>>>(gine_w1, gine_w2, mlp_w1, mlp_w2,
                                         attn_in_w, attn_out_w,
                                         g1t, g2t, m1t, m2t, ait, aot);
    k_h0<<<dim3(8192), B, 0, stream>>>(x, np_w, np_b, h16);
    k_zero2<<<dim3(128), B, 0, stream>>>(counts, cursor);
    k_count<<<dim3(2048), B, 0, stream>>>(ei, counts);
    k_scan<<<dim3(1), dim3(1024), 0, stream>>>(counts, rowp);
    k_fill<<<dim3(2048), B, 0, stream>>>(ei, rowp, cursor, srcp, eidp);
    k_edge<<<dim3(2048), B, 0, stream>>>(edge_attr, ep_w, ep_b, eidp, e16p);

    const f16* nf = (const f16*)nullptr;
    const float* nff = (const float*)nullptr;
    for (int l = 0; l < L_; l++) {
        k_aggr<<<dim3(8192), B, 0, stream>>>(h16, e16p, srcp, rowp, eps, l, zin);
        k_gq<<<dim3(512, 5), B, 0, stream>>>(
            zin, g1t + l * 32768, gine_b1 + l * 256, u16,
            h16, ait + l * 49152, attn_in_b + l * 384, qbuf, kbuf, vt);
        k_attn<<<dim3(2048), B, 0, stream>>>(qbuf, kbuf, vt, o16);
        k_g2<<<dim3(512, 2), B, 0, stream>>>(
            u16, g2t + l * 32768, gine_b2 + l * 128,
            o16, aot + l * 16384, attn_out_b + l * 128,
            h16, tloc, tattn, statsA, statsB);
        k_fin<<<dim3(2), dim3(1024), 0, stream>>>(
            statsA, statsB, bn1_g + l * 128, bn1_b + l * 128,
            bn2_g + l * 128, bn2_b + l * 128, scsh1, scsh2);
        k_g128<1, true><<<dim3(512, 2), B, 0, stream>>>(
            nf, m1t + l * 32768, mlp_b1 + l * 256, tloc, tattn, scsh1, scsh2,
            u16, out16, 256);
        k_g2<<<dim3(512, 1), B, 0, stream>>>(
            u16, m2t + l * 32768, mlp_b2 + l * 128,
            u16, m2t + l * 32768, mlp_b2 + l * 128,
            out16, zin, zin, statsA, statsA);
        k_fin<<<dim3(1), dim3(1024), 0, stream>>>(
            statsA, statsA, bn3_g + l * 128, bn3_b + l * 128,
            bn3_g + l * 128, bn3_b + l * 128, scsh3, scsh3);
        k_bn3<<<dim3(8192), B, 0, stream>>>(zin, scsh3, h16);
    }
    k_pool<<<dim3(64), B, 0, stream>>>(h16, ln_g, ln_b, head_w1, head_b1,
                                       head_w2, head_b2, (float*)d_out);
}